// Round 3
// baseline (130.832 us; speedup 1.0000x reference)
//
#include <hip/hip_runtime.h>
#include <math.h>

#define LOG2PI_F   1.8378770664093453f
#define LOGPI_F    1.1447298858494002f
#define LOG2_F     0.6931471805599453f
#define L2E_F      1.4426950408889634f
#define ERF3OS2    0.9973002039367398f   // erf(3/sqrt(2)), wf = 3.0 (compile-time)
#define WF         3.0f
#define NMC        1024
#define NPAIR      512
#define LOGN_F     6.9314718055994531f   // log(1024)
#define LOGGAMMA15 (-0.12078223763524522f) // log(Gamma(1.5))

typedef float v2f __attribute__((ext_vector_type(2)));

#if defined(__has_builtin)
#if __has_builtin(__builtin_amdgcn_exp2f)
#define EXP2(v) __builtin_amdgcn_exp2f(v)
#else
#define EXP2(v) __expf((v) * LOG2_F)
#endif
#else
#define EXP2(v) __expf((v) * LOG2_F)
#endif

// ---------------- Kernel A: per-n tables + header + zero output ----------------
// Pair-SoA layout for packed math in kernel B:
//   tabA[c][pair] = float4 {txc0, txc1, gc0, gc1}
//   tabZ[c][pair] = float2 {zc0, zc1}
// txc = inv_sn2 * tx * L2E ; gc = 2*inv_sn2*G*L2E ; zc = (B - 0.5*inv_sn2*tx^2 - inv_sn2*G^2)*L2E
// with B = -log G + lptx + log(I_diff) - log N + lw[3+c]  (validated rounds 1-2).
// s1*log2e = Cm + x*txc + zc + y*gc = bp ;  s2*log2e = bp - 2*y*gc = bm
// term = 2^bp - 2^bm.
__global__ void precompute_kernel(const float* __restrict__ ku12,
                                  const float* __restrict__ ku23,
                                  const float* __restrict__ ku13,
                                  const float* __restrict__ sbp,
                                  const float* __restrict__ snp,
                                  const float* __restrict__ I1p,
                                  const float* __restrict__ I2p,
                                  const float* __restrict__ I3p,
                                  const float* __restrict__ w,
                                  float* __restrict__ tabA,
                                  float* __restrict__ tabZ,
                                  float* __restrict__ hdr,
                                  float* __restrict__ out) {
    const int n = threadIdx.x;           // 1024 threads, 1 block
    const float sigma_b = sbp[0], sigma_n = snp[0];
    const float I1 = I1p[0], I2 = I2p[0], I3 = I3p[0];
    const float inv_sn2 = 1.0f / (sigma_n * sigma_n);

    // softmax(log-weights): lw = w - logsumexp(w)
    float wv[6];
    #pragma unroll
    for (int i = 0; i < 6; ++i) wv[i] = w[i];
    float wm = wv[0];
    #pragma unroll
    for (int i = 1; i < 6; ++i) wm = fmaxf(wm, wv[i]);
    float wsum = 0.f;
    #pragma unroll
    for (int i = 0; i < 6; ++i) wsum += __expf(wv[i] - wm);
    const float lsew = wm + __logf(wsum);

    const float* kus[3] = {ku12, ku23, ku13};
    const float Ias[3] = {I1, I2, I1};
    const float Ibs[3] = {I2, I3, I3};
    const float gb = rsqrtf(2.0f * (float)M_PI * sigma_b * sigma_b);

    const int pair = n >> 1;
    const int sub  = n & 1;

    #pragma unroll
    for (int c = 0; c < 3; ++c) {
        const float Ia = Ias[c], Ib = Ibs[c];
        const float gap = Ib - Ia;
        const float I_min  = Ia + 0.5f * gap * (1.0f - ERF3OS2);
        const float I_diff = gap * ERF3OS2;
        const float add_c  = __logf(I_diff) - LOGN_F + (wv[3 + c] - lsew);
        const float ku = kus[c][n];
        const float tx = ku * I_diff + I_min;
        const float v  = 2.0f * (tx - Ia) / gap - 1.0f;
        const float ei = erfinvf(v);
        const float ei2 = ei * ei;
        const float G   = gap * gb * __expf(-ei2);
        const float lptx = -__logf(2.0f * WF * gap) + 0.5f * LOG2PI_F + ei2;
        const float B = -__logf(G) + lptx + add_c;

        const float txc = inv_sn2 * tx * L2E_F;
        const float gc  = 2.0f * inv_sn2 * G * L2E_F;
        const float zc  = (B - 0.5f * inv_sn2 * tx * tx - inv_sn2 * G * G) * L2E_F;

        tabA[(c * NPAIR + pair) * 4 + sub]     = txc;
        tabA[(c * NPAIR + pair) * 4 + 2 + sub] = gc;
        tabZ[(c * NPAIR + pair) * 2 + sub]     = zc;
    }

    if (n == 0) {
        const float lsn = __logf(sigma_n);
        hdr[0] = inv_sn2;
        hdr[1] = -2.f * lsn - 0.5f * LOG2PI_F - 0.5f * LOGPI_F;        // C_A (A_m = C_A + log y)
        hdr[2] = LOG2_F - LOGGAMMA15 - 4.f * lsn - 0.5f * LOG2PI_F;    // K_int
        hdr[3] = I1; hdr[4] = I2; hdr[5] = I3;
        hdr[6] = wv[0] - lsew; hdr[7] = wv[1] - lsew; hdr[8] = wv[2] - lsew;
        out[0] = 0.f;
    }
}

// ---------------- Kernel B: main loop ----------------
// Block = 512 threads = 8 waves. Lane (0..63) -> data point m; wave -> 64 n-pairs.
#define WAVES  8
#define PCHUNK 64   // pairs per wave = NPAIR / WAVES

__global__ __launch_bounds__(512) void
main_kernel(const float* __restrict__ xg, const float* __restrict__ yg,
            const float4* __restrict__ tabA, const float2* __restrict__ tabZ,
            const float* __restrict__ hdr, float* __restrict__ out, int M) {
    const int lane = threadIdx.x & 63;
    const int wave = threadIdx.x >> 6;
    const int m = blockIdx.x * 64 + lane;
    const bool valid = (m < M);
    const float x = valid ? xg[m] : 0.5f;
    const float y = valid ? yg[m] : 0.5f;

    const float inv_sn2 = hdr[0];
    const float Cm = -(fmaf(0.5f * x, x, y * y)) * inv_sn2 * L2E_F;

    // wave-min of y for the uniform bm-skip test
    float ymin = y;
    #pragma unroll
    for (int o = 32; o > 0; o >>= 1) ymin = fminf(ymin, __shfl_xor(ymin, o));
    const float ymin_s = __builtin_amdgcn_readfirstlane(ymin);

    const v2f x2  = {x, x};
    const v2f y2  = {y, y};
    const v2f Cm2 = {Cm, Cm};
    const v2f n2y = {-2.f * y, -2.f * y};

    v2f A0 = {0.f, 0.f}, B0 = {0.f, 0.f};
    v2f A1 = {0.f, 0.f}, B1 = {0.f, 0.f};
    v2f A2 = {0.f, 0.f}, B2 = {0.f, 0.f};

    const int p0 = __builtin_amdgcn_readfirstlane(wave * PCHUNK);

    #pragma unroll 4
    for (int i = 0; i < PCHUNK; ++i) {
        const int pr = p0 + i;
        #pragma unroll
        for (int c = 0; c < 3; ++c) {
            const float4 t = tabA[c * NPAIR + pr];     // {tx0,tx1,g0,g1}
            const float2 z = tabZ[c * NPAIR + pr];     // {z0,z1}
            const v2f tx2 = {t.x, t.y};
            const v2f g2  = {t.z, t.w};
            const v2f z2  = {z.x, z.y};
            const v2f core = __builtin_elementwise_fma(x2, tx2, z2);
            const v2f bC   = core + Cm2;
            const v2f bp   = __builtin_elementwise_fma(y2, g2, bC);
            const v2f ea   = {EXP2(bp[0]), EXP2(bp[1])};
            v2f* Ac = (c == 0) ? &A0 : (c == 1) ? &A1 : &A2;
            v2f* Bc = (c == 0) ? &B0 : (c == 1) ? &B1 : &B2;
            *Ac += ea;
            const float gmin = __builtin_amdgcn_readfirstlane(fminf(t.z, t.w));
            if (ymin_s * gmin <= 10.0f) {              // bm term not negligible
                const v2f bm = __builtin_elementwise_fma(n2y, g2, bp);
                const v2f eb = {EXP2(bm[0]), EXP2(bm[1])};
                *Bc += eb;
            }
        }
    }

    __shared__ float pac[WAVES][3][64];
    pac[wave][0][lane] = (A0[0] + A0[1]) - (B0[0] + B0[1]);
    pac[wave][1][lane] = (A1[0] + A1[1]) - (B1[0] + B1[1]);
    pac[wave][2][lane] = (A2[0] + A2[1]) - (B2[0] + B2[1]);
    __syncthreads();

    if (wave == 0) {
        const float ly = __logf(y);
        const float A_m = hdr[1] + ly;
        const float base_int = hdr[2] + 2.f * ly - y * y * inv_sn2;
        float vals[6];
        #pragma unroll
        for (int c = 0; c < 3; ++c) {
            const float dxi = x - hdr[3 + c];
            vals[c] = hdr[6 + c] + base_int - 0.5f * dxi * dxi * inv_sn2;
        }
        #pragma unroll
        for (int c = 0; c < 3; ++c) {
            float s = 0.f;
            #pragma unroll
            for (int wv2 = 0; wv2 < WAVES; ++wv2) s += pac[wv2][c][lane];
            vals[3 + c] = A_m + __logf(fmaxf(s, 1e-38f));
        }
        float mm = vals[0];
        #pragma unroll
        for (int i = 1; i < 6; ++i) mm = fmaxf(mm, vals[i]);
        float se = 0.f;
        #pragma unroll
        for (int i = 0; i < 6; ++i) se += __expf(vals[i] - mm);
        const float log_mix = mm + __logf(se);
        float contrib = valid ? -log_mix : 0.f;
        #pragma unroll
        for (int off = 32; off > 0; off >>= 1) contrib += __shfl_down(contrib, off);
        if (lane == 0) atomicAdd(out, contrib);
    }
}

extern "C" void kernel_launch(void* const* d_in, const int* in_sizes, int n_in,
                              void* d_out, int out_size, void* d_ws, size_t ws_size,
                              hipStream_t stream) {
    const float* x    = (const float*)d_in[0];
    const float* y    = (const float*)d_in[1];
    const float* ku12 = (const float*)d_in[2];
    const float* ku23 = (const float*)d_in[3];
    const float* ku13 = (const float*)d_in[4];
    const float* sb   = (const float*)d_in[5];
    const float* sn   = (const float*)d_in[6];
    const float* I1   = (const float*)d_in[7];
    const float* I2   = (const float*)d_in[8];
    const float* I3   = (const float*)d_in[9];
    const float* w    = (const float*)d_in[10];
    const int M = in_sizes[0];

    float* tabA = (float*)d_ws;                                   // 3*512*4 floats = 24 KB
    float* tabZ = (float*)((char*)d_ws + 3 * NPAIR * 4 * sizeof(float)); // 12 KB
    float* hdr  = (float*)((char*)d_ws + 3 * NPAIR * 6 * sizeof(float));
    float* out  = (float*)d_out;

    precompute_kernel<<<1, NMC, 0, stream>>>(ku12, ku23, ku13, sb, sn, I1, I2, I3, w,
                                             tabA, tabZ, hdr, out);
    const int blocks = (M + 63) / 64;
    main_kernel<<<blocks, 512, 0, stream>>>(x, y, (const float4*)tabA, (const float2*)tabZ,
                                            hdr, out, M);
}